// Round 3
// baseline (1049.124 us; speedup 1.0000x reference)
//
#include <hip/hip_runtime.h>
#include <stdint.h>
#include <math.h>

// LightweightTransformerLayer fused implementation for gfx950 (round 2 resubmit).
// B=8, C=256, N=64, P=256; 512 sequences of [256 tokens x 256 ch].
//
// prep: fp32->bf16 weights into ws in FRAG-LINEAR layout (each 16x32 MFMA tile
//       = 64 contiguous uint4, one per lane) so every weight fragment load is a
//       fully coalesced 1KB global read (L1/L2-served). W_q pre-scaled by
//       SCALE*log2e for exp2-domain softmax.
// k1  : per-sequence WG (512 thr, 64KB LDS -> 2 WG/CU): LN1 from direct global
//       reads (no LDS), h in registers; per head: K/V gen -> LDS, Q gen, flash
//       attention (S^T = K Q^T trick, in-register shuffle transposes); O frags
//       spilled to global scratch (same-wave RAW only, no barriers); proj +
//       bias + residual -> x2 fp32 to d_out. 8 barriers total.
// k2  : per-64-token WG (512 thr, 68KB LDS -> 2 WG/CU): x2 -> LN2 (stats via
//       shfl + tiny LDS) -> h2 frags in LDS -> MLP1 + exact GELU -> m1 frags
//       (hidden dim halved, GEMM2 acc in regs across halves) -> MLP2 ->
//       residual RMW d_out.

#define DEV static __device__ __forceinline__

typedef __bf16 bf16x8 __attribute__((ext_vector_type(8)));
typedef float  f32x4  __attribute__((ext_vector_type(4)));

union B8 { bf16x8 v; uint4 q; uint32_t u[4]; uint16_t h[8]; };

DEV uint16_t f2bf(float f) {
  uint32_t u = __float_as_uint(f);
  return (uint16_t)((u + 0x7FFFu + ((u >> 16) & 1u)) >> 16);  // RNE
}
DEV float bf2f(uint16_t h) { return __uint_as_float(((uint32_t)h) << 16); }
DEV uint32_t pk2(float a, float b) { return (uint32_t)f2bf(a) | ((uint32_t)f2bf(b) << 16); }

DEV f32x4 mfma16(const B8& a, const B8& b, f32x4 c) {
  return __builtin_amdgcn_mfma_f32_16x16x32_bf16(a.v, b.v, c, 0, 0, 0);
}

DEV uint32_t shfl_u(uint32_t v, int src) { return (uint32_t)__shfl((int)v, src, 64); }

DEV B8 mk(const uint32_t* w) {
  B8 x; x.u[0] = w[0]; x.u[1] = w[1]; x.u[2] = w[2]; x.u[3] = w[3]; return x;
}

// Transpose C-frags (4 row-tiles of 16, regs packed as bf16 pairs pk0=(r0,r1),
// pk1=(r2,r3)) into an A/B-frag. Verified (round 1 passed end-to-end):
// C/D col=lane&15, row=(lane>>4)*4+i ; A/B idx=lane&15, k-octet=(lane>>4)*8.
DEV void xpose(const uint32_t* pk0, const uint32_t* pk1, int kd, int g, int r, uint32_t* out) {
  const int sA = 32 * (g & 1) + r;
  const int sB = sA + 16;
  const int tA = 2 * kd, tB = 2 * kd + 1;
  uint32_t a0 = shfl_u(pk0[tA], sA), b0 = shfl_u(pk0[tB], sA);
  uint32_t a1 = shfl_u(pk1[tA], sA), b1 = shfl_u(pk1[tB], sA);
  uint32_t a2 = shfl_u(pk0[tA], sB), b2 = shfl_u(pk0[tB], sB);
  uint32_t a3 = shfl_u(pk1[tA], sB), b3 = shfl_u(pk1[tB], sB);
  const bool hi = g >= 2;
  out[0] = hi ? b0 : a0;
  out[1] = hi ? b1 : a1;
  out[2] = hi ? b2 : a2;
  out[3] = hi ? b3 : a3;
}

// ---------------------------------------------------------------------------
// prep: weights -> bf16 FRAG-LINEAR. For a matrix [R][C] (row-major, C=in):
// tile (tr, tk) covers rows 16tr..+16, cols 32tk..+32; stored at
// (tr*(C/32)+tk)*512 + lane*8 + j  with lane = (row&15) + 16*((col>>3)&3),
// j = col&7.  Segments (bf16 elems): wqkv_f @0 (196608, first 65536 = W_q
// scaled), wproj_f @196608 (65536), w1_f @262144 (131072), w2_f @393216 (131072).
__global__ void transformer_prep(const float* __restrict__ wqkv,
                                 const float* __restrict__ wproj,
                                 const float* __restrict__ w1,
                                 const float* __restrict__ w2,
                                 uint16_t* __restrict__ dst) {
  int e = blockIdx.x * 256 + threadIdx.x;  // grid 2048*256 = 524288 exactly
  const float* src; int C, local;
  if (e < 196608)      { src = wqkv;  C = 256; local = e; }
  else if (e < 262144) { src = wproj; C = 256; local = e - 196608; }
  else if (e < 393216) { src = w1;    C = 256; local = e - 262144; }
  else                 { src = w2;    C = 512; local = e - 393216; }
  int k32 = C >> 5;
  int tile = local >> 9, within = local & 511;
  int ln = within >> 3, j = within & 7;
  int tr = tile / k32, tk = tile - tr * k32;
  int row = tr * 16 + (ln & 15), col = tk * 32 + (ln >> 4) * 8 + j;
  float v = src[row * C + col];
  if (e < 65536) v *= 0.18033688011112042f;  // SCALE * log2(e) folded into W_q
  dst[e] = f2bf(v);
}

// ---------------------------------------------------------------------------
// k1 LDS map (65536 B): K bf16 [q 256][d 64] pitch 128B @0 (32768),
//                       V^T bf16 [d 64][q 256] pitch 512B @32768 (32768).
// Row-major tiles swizzled: byte ^= (row&7)<<4.
__global__ __launch_bounds__(512, 4) void transformer_k1(
    const float* __restrict__ x,
    const float* __restrict__ bproj,
    const float* __restrict__ ln1g, const float* __restrict__ ln1b,
    const uint16_t* __restrict__ wf,      // wqkv_f @0, wproj_f @196608
    uint16_t* __restrict__ osc,           // O frag scratch, 64MB
    float* __restrict__ out) {
  __shared__ __attribute__((aligned(16))) uint8_t lds[65536];
  const int tid = threadIdx.x;
  const int lane = tid & 63;
  const int wv = tid >> 6;       // wave 0..7, owns token rows 32*wv..+32
  const int r = lane & 15;
  const int g = lane >> 4;
  const int s = blockIdx.x;      // sequence = b*64 + n
  const int bb = s >> 6, nn = s & 63;
  const float* xs = x + (size_t)bb * 4194304 + (size_t)nn * 256;  // (c,p) at c*16384+p
  float* outp = out + (size_t)bb * 4194304 + (size_t)nn * 256;
  const f32x4 fz = {0.f, 0.f, 0.f, 0.f};

  // ============ Phase 1: x -> LN1 -> h as register frags (no LDS) ===========
  // hfrag[rt][kt]: h[p = 32wv+16rt+r][c = 32kt+8g .. +8] as bf16x8.
  // Global loads: per inst 4 c-rows x 16 consecutive p = 4 full 64B sectors.
  uint32_t hfrag[2][8][4];
  float s1[2] = {0.f, 0.f}, s2[2] = {0.f, 0.f};
#pragma unroll
  for (int rt = 0; rt < 2; ++rt) {
    int p = 32 * wv + 16 * rt + r;
#pragma unroll
    for (int kt = 0; kt < 8; ++kt) {
      int c0 = 32 * kt + 8 * g;
      float v[8];
#pragma unroll
      for (int j = 0; j < 8; ++j) {
        v[j] = xs[(size_t)(c0 + j) * 16384 + p];
        s1[rt] += v[j];
        s2[rt] += v[j] * v[j];
      }
#pragma unroll
      for (int w = 0; w < 4; ++w) hfrag[rt][kt][w] = pk2(v[2 * w], v[2 * w + 1]);
    }
  }
  float mu[2], rs[2];
#pragma unroll
  for (int rt = 0; rt < 2; ++rt) {  // lanes r,r+16,r+32,r+48 share a token row
    float a = s1[rt]; a += __shfl_xor(a, 16, 64); a += __shfl_xor(a, 32, 64);
    float b = s2[rt]; b += __shfl_xor(b, 16, 64); b += __shfl_xor(b, 32, 64);
    mu[rt] = a * (1.0f / 256.0f);
    float var = b * (1.0f / 256.0f) - mu[rt] * mu[rt];
    rs[rt] = rsqrtf(var + 1e-5f);
  }
#pragma unroll
  for (int kt = 0; kt < 8; ++kt) {  // normalize in place
    int c0 = 32 * kt + 8 * g;
    f32x4 gA = *(const f32x4*)(ln1g + c0), gB = *(const f32x4*)(ln1g + c0 + 4);
    f32x4 bA = *(const f32x4*)(ln1b + c0), bB = *(const f32x4*)(ln1b + c0 + 4);
#pragma unroll
    for (int rt = 0; rt < 2; ++rt) {
#pragma unroll
      for (int w = 0; w < 4; ++w) {
        uint32_t pw = hfrag[rt][kt][w];
        float lo = bf2f((uint16_t)(pw & 0xFFFFu));
        float hi = bf2f((uint16_t)(pw >> 16));
        float glo = (w < 2) ? gA[2 * w] : gB[2 * w - 4];
        float ghi = (w < 2) ? gA[2 * w + 1] : gB[2 * w - 3];
        float blo = (w < 2) ? bA[2 * w] : bB[2 * w - 4];
        float bhi = (w < 2) ? bA[2 * w + 1] : bB[2 * w - 3];
        lo = (lo - mu[rt]) * rs[rt] * glo + blo;
        hi = (hi - mu[rt]) * rs[rt] * ghi + bhi;
        hfrag[rt][kt][w] = pk2(lo, hi);
      }
    }
  }

  // ============ Phase 2: attention heads ====================================
#pragma unroll 1
  for (int hd = 0; hd < 4; ++hd) {
    // ---- K (m=0) and V^T (m=1) generation; W frags straight from global
#pragma unroll
    for (int m = 0; m < 2; ++m) {
      f32x4 acc[2][4];
#pragma unroll
      for (int rt = 0; rt < 2; ++rt)
#pragma unroll
        for (int ct = 0; ct < 4; ++ct) acc[rt][ct] = fz;
#pragma unroll
      for (int kt = 0; kt < 8; ++kt) {
#pragma unroll
        for (int ct = 0; ct < 4; ++ct) {
          B8 wfr;
          wfr.q = *(const uint4*)(wf + (size_t)((((m + 1) * 16 + hd * 4 + ct) * 8 + kt) * 512) + lane * 8);
#pragma unroll
          for (int rt = 0; rt < 2; ++rt) {
            B8 a = mk(hfrag[rt][kt]);
            acc[rt][ct] = mfma16(a, wfr, acc[rt][ct]);
          }
        }
      }
#pragma unroll
      for (int rt = 0; rt < 2; ++rt) {
#pragma unroll
        for (int ct = 0; ct < 4; ++ct) {
          int d = 16 * ct + r;
          int q0 = 32 * wv + 16 * rt + 4 * g;
          if (m == 0) {  // K[q][d], pitch 128B
#pragma unroll
            for (int i = 0; i < 4; ++i) {
              int qq = q0 + i;
              *(uint16_t*)(lds + ((qq * 128 + d * 2) ^ ((qq & 7) << 4))) = f2bf(acc[rt][ct][i]);
            }
          } else {       // V^T[d][q], pitch 512B, 4 consecutive q packed
            uint2 pv;
            pv.x = pk2(acc[rt][ct][0], acc[rt][ct][1]);
            pv.y = pk2(acc[rt][ct][2], acc[rt][ct][3]);
            *(uint2*)(lds + ((32768 + d * 512 + q0 * 2) ^ ((d & 7) << 4))) = pv;
          }
        }
      }
    }
    __syncthreads();  // K/V visible (also: prior flash reads done before write)

    // ---- flash attention; pt-sequential (2 x 16 query rows) to cap VGPRs
#pragma unroll 1
    for (int pt = 0; pt < 2; ++pt) {
      // Q^T[d 64][p 16] = (scaled Wq) x h ; Wq frags from global
      f32x4 qT[4];
#pragma unroll
      for (int mt = 0; mt < 4; ++mt) qT[mt] = fz;
#pragma unroll
      for (int kt = 0; kt < 8; ++kt) {
        B8 hb = mk(hfrag[pt][kt]);
#pragma unroll
        for (int mt = 0; mt < 4; ++mt) {
          B8 wa;
          wa.q = *(const uint4*)(wf + (size_t)(((hd * 4 + mt) * 8 + kt) * 512) + lane * 8);
          qT[mt] = mfma16(wa, hb, qT[mt]);
        }
      }
      uint32_t pq0[4], pq1[4];
#pragma unroll
      for (int mt = 0; mt < 4; ++mt) {
        pq0[mt] = pk2(qT[mt][0], qT[mt][1]);
        pq1[mt] = pk2(qT[mt][2], qT[mt][3]);
      }
      uint32_t qb[2][4];
#pragma unroll
      for (int kd = 0; kd < 2; ++kd) xpose(pq0, pq1, kd, g, r, qb[kd]);

      float m_ = -1e30f, l_ = 0.f;
      f32x4 oT[4];
#pragma unroll
      for (int dt = 0; dt < 4; ++dt) oT[dt] = fz;

#pragma unroll 1
      for (int chk = 0; chk < 4; ++chk) {  // 64 keys per step
        f32x4 sT[4];
#pragma unroll
        for (int qt = 0; qt < 4; ++qt) sT[qt] = fz;
#pragma unroll
        for (int kd = 0; kd < 2; ++kd) {
          B8 qf = mk(qb[kd]);
#pragma unroll
          for (int qt = 0; qt < 4; ++qt) {
            int qq = chk * 64 + 16 * qt + r;
            B8 ka;
            ka.q = *(const uint4*)(lds + ((qq * 128 + (32 * kd + 8 * g) * 2) ^ ((qq & 7) << 4)));
            sT[qt] = mfma16(ka, qf, sT[qt]);  // S^T[q][p], log2-domain
          }
        }
        // online softmax over q (16 in-lane values + g-butterfly)
        float tmax = sT[0][0];
#pragma unroll
        for (int qt = 0; qt < 4; ++qt)
#pragma unroll
          for (int i = 0; i < 4; ++i) tmax = fmaxf(tmax, sT[qt][i]);
        tmax = fmaxf(tmax, __shfl_xor(tmax, 16, 64));
        tmax = fmaxf(tmax, __shfl_xor(tmax, 32, 64));
        float mn = fmaxf(m_, tmax);
        float fcor = exp2f(m_ - mn);
        float ts = 0.f;
#pragma unroll
        for (int qt = 0; qt < 4; ++qt)
#pragma unroll
          for (int i = 0; i < 4; ++i) {
            float e = exp2f(sT[qt][i] - mn);
            sT[qt][i] = e;
            ts += e;
          }
        ts += __shfl_xor(ts, 16, 64);
        ts += __shfl_xor(ts, 32, 64);
        l_ = l_ * fcor + ts;
        m_ = mn;
#pragma unroll
        for (int dt = 0; dt < 4; ++dt)
#pragma unroll
          for (int i = 0; i < 4; ++i) oT[dt][i] *= fcor;
        // P^T C-frags -> PV B-frags (in-register shuffle transpose)
        uint32_t pp0[4], pp1[4];
#pragma unroll
        for (int qt = 0; qt < 4; ++qt) {
          pp0[qt] = pk2(sT[qt][0], sT[qt][1]);
          pp1[qt] = pk2(sT[qt][2], sT[qt][3]);
        }
#pragma unroll
        for (int qk = 0; qk < 2; ++qk) {
          uint32_t pb[4];
          xpose(pp0, pp1, qk, g, r, pb);
          B8 pf = mk(pb);
#pragma unroll
          for (int dt = 0; dt < 4; ++dt) {
            B8 va;
            va.q = *(const uint4*)(lds + ((32768 + (16 * dt + r) * 512 + (chk * 64 + 32 * qk + 8 * g) * 2) ^ ((r & 7) << 4)));
            oT[dt] = mfma16(va, pf, oT[dt]);  // O^T[d][p]
          }
        }
      }
      float inv = 1.0f / l_;
      uint32_t po0[4], po1[4];
#pragma unroll
      for (int dt = 0; dt < 4; ++dt) {
        po0[dt] = pk2(oT[dt][0] * inv, oT[dt][1] * inv);
        po1[dt] = pk2(oT[dt][2] * inv, oT[dt][3] * inv);
      }
      // O as proj A-frags -> global scratch (same-wave RAW only, coalesced 1KB)
#pragma unroll
      for (int kd = 0; kd < 2; ++kd) {
        uint32_t ofr[4];
        xpose(po0, po1, kd, g, r, ofr);
        B8 t; t.u[0] = ofr[0]; t.u[1] = ofr[1]; t.u[2] = ofr[2]; t.u[3] = ofr[3];
        *(uint4*)(osc + (size_t)((s * 16 + 2 * wv + pt) * 8 + 2 * hd + kd) * 512 + lane * 8) = t.q;
      }
    }
    __syncthreads();  // flash K/V reads done before next head overwrites
  }

  // ============ Phase 3: proj + bias + residual -> x2 fp32 (d_out) ==========
  // No LDS, no barriers: A-frags from osc (own wave's), W frags from global.
#pragma unroll 1
  for (int q3 = 0; q3 < 4; ++q3) {  // 64 output channels per step
    f32x4 acc[2][4];
#pragma unroll
    for (int rt = 0; rt < 2; ++rt)
#pragma unroll
      for (int ct = 0; ct < 4; ++ct) acc[rt][ct] = fz;
#pragma unroll
    for (int kt = 0; kt < 8; ++kt) {
      B8 a[2];
#pragma unroll
      for (int rt = 0; rt < 2; ++rt)
        a[rt].q = *(const uint4*)(osc + (size_t)((s * 16 + 2 * wv + rt) * 8 + kt) * 512 + lane * 8);
#pragma unroll
      for (int ct = 0; ct < 4; ++ct) {
        B8 wfr;
        wfr.q = *(const uint4*)(wf + 196608 + (size_t)(((q3 * 4 + ct) * 8 + kt) * 512) + lane * 8);
#pragma unroll
        for (int rt = 0; rt < 2; ++rt) acc[rt][ct] = mfma16(a[rt], wfr, acc[rt][ct]);
      }
    }
#pragma unroll
    for (int rt = 0; rt < 2; ++rt) {
#pragma unroll
      for (int ct = 0; ct < 4; ++ct) {
        int c = q3 * 64 + 16 * ct + r;
        float bias = bproj[c];
        int p0 = 32 * wv + 16 * rt + 4 * g;
        f32x4 res = *(const f32x4*)(xs + (size_t)c * 16384 + p0);
        f32x4 x2v;
#pragma unroll
        for (int i = 0; i < 4; ++i) x2v[i] = acc[rt][ct][i] + bias + res[i];
        *(f32x4*)(outp + (size_t)c * 16384 + p0) = x2v;
      }
    }
  }
}

// ---------------------------------------------------------------------------
// k2: LN2 + MLP + residual. WG = (sequence s, 64-token group tg).
// LDS (68608 B): h2 frags 32KB @0, m1 frags (per hidden-half) 32KB @32768,
//                stat partials @65536 (1KB), mu/rs @66560 (512B).
__global__ __launch_bounds__(512, 4) void transformer_k2(
    const float* __restrict__ ln2g, const float* __restrict__ ln2b,
    const uint16_t* __restrict__ w1f, const uint16_t* __restrict__ w2f,
    const float* __restrict__ bm1, const float* __restrict__ bm2,
    float* __restrict__ out) {
  __shared__ __attribute__((aligned(16))) uint8_t lds[68608];
  const int tid = threadIdx.x;
  const int lane = tid & 63;
  const int wv = tid >> 6;
  const int r = lane & 15, g = lane >> 4;
  const int bid = blockIdx.x;
  const int s = bid >> 2, tg = bid & 3;
  const int bb = s >> 6, nn = s & 63;
  float* outp = out + (size_t)bb * 4194304 + (size_t)nn * 256;
  const int tokbase = tg * 64;
  const f32x4 fz = {0.f, 0.f, 0.f, 0.f};
  const int mtw = wv & 3, kth = wv >> 2;      // wave -> (row-tile, c-half)
  const int p = tokbase + 16 * mtw + r;       // this lane's token

  // ---- read x2 slice (kept in regs), accumulate LN2 partial stats ----------
  float v[4][8];
  float s1 = 0.f, s2 = 0.f;
#pragma unroll
  for (int k2l = 0; k2l < 4; ++k2l) {
    int c0 = (kth * 4 + k2l) * 32 + 8 * g;
#pragma unroll
    for (int j = 0; j < 8; ++j) {
      float t = outp[(size_t)(c0 + j) * 16384 + p];
      v[k2l][j] = t;
      s1 += t;
      s2 += t * t;
    }
  }
  s1 += __shfl_xor(s1, 16, 64); s1 += __shfl_xor(s1, 32, 64);
  s2 += __shfl_xor(s2, 16, 64); s2 += __shfl_xor(s2, 32, 64);
  if (g == 0) {  // partial over this wave-half's 128 channels
    float2 pr; pr.x = s1; pr.y = s2;
    *(float2*)(lds + 65536 + ((16 * mtw + r) * 2 + kth) * 8) = pr;
  }
  __syncthreads();
  if (tid < 64) {
    float2 a = *(const float2*)(lds + 65536 + (tid * 2 + 0) * 8);
    float2 b = *(const float2*)(lds + 65536 + (tid * 2 + 1) * 8);
    float su = a.x + b.x, sq = a.y + b.y;
    float m = su * (1.0f / 256.0f);
    float var = sq * (1.0f / 256.0f) - m * m;
    float2 st; st.x = m; st.y = rsqrtf(var + 1e-5f);
    *(float2*)(lds + 66560 + tid * 8) = st;
  }
  __syncthreads();
  float2 st = *(const float2*)(lds + 66560 + (16 * mtw + r) * 8);
  // ---- normalize + pack h2 frags into LDS (frag-linear, conflict-free) -----
#pragma unroll
  for (int k2l = 0; k2l < 4; ++k2l) {
    int kt = kth * 4 + k2l;
    int c0 = kt * 32 + 8 * g;
    f32x4 gA = *(const f32x4*)(ln2g + c0), gB = *(const f32x4*)(ln2g + c0 + 4);
    f32x4 bA = *(const f32x4*)(ln2b + c0), bB = *(const f32x4*)(ln2b + c0 + 4);
    float nv[8];
#pragma unroll
    for (int j = 0; j < 8; ++j) {
      float gg = (j < 4) ? gA[j] : gB[j - 4];
      float bb2 = (j < 4) ? bA[j] : bB[j - 4];
      nv[j] = (v[k2l][j] - st.x) * st.y * gg + bb2;
    }
    B8 t;
#pragma unroll
    for (int w = 0; w < 4; ++w) t.u[w] = pk2(nv[2 * w], nv[2 * w + 1]);
    *(uint4*)(lds + (mtw * 8 + kt) * 1024 + lane * 16) = t.q;
  }
  __syncthreads();

  // ---- MLP: hidden dim in 2 halves; GEMM2 accumulates in regs across halves
  f32x4 acc2[4][2];
#pragma unroll
  for (int mt = 0; mt < 4; ++mt)
#pragma unroll
    for (int nt = 0; nt < 2; ++nt) acc2[mt][nt] = fz;

#pragma unroll 1
  for (int half = 0; half < 2; ++half) {
    // GEMM1: [64 tok][256 c] x W1half^T -> wave owns 32 hidden cols
    f32x4 acc1[4][2];
#pragma unroll
    for (int mt = 0; mt < 4; ++mt)
#pragma unroll
      for (int nt = 0; nt < 2; ++nt) acc1[mt][nt] = fz;
#pragma unroll
    for (int kt = 0; kt < 8; ++kt) {
      B8 a[4];
#pragma unroll
      for (int mt = 0; mt < 4; ++mt)
        a[mt].q = *(const uint4*)(lds + (mt * 8 + kt) * 1024 + lane * 16);
#pragma unroll
      for (int nt = 0; nt < 2; ++nt) {
        B8 bfr;
        bfr.q = *(const uint4*)(w1f + (size_t)((((half * 16 + wv * 2 + nt) * 8) + kt) * 512) + lane * 8);
#pragma unroll
        for (int mt = 0; mt < 4; ++mt) acc1[mt][nt] = mfma16(a[mt], bfr, acc1[mt][nt]);
      }
    }
    if (half) __syncthreads();  // GEMM2(half0) m1 reads done before overwrite
    // bias + exact GELU + scatter m1 C-frags into A-frag-linear LDS
#pragma unroll
    for (int nt = 0; nt < 2; ++nt) {
      int nl = wv * 32 + 16 * nt + r;        // hidden index within half
      float bias = bm1[half * 256 + nl];
#pragma unroll
      for (int mt = 0; mt < 4; ++mt) {
#pragma unroll
        for (int i = 0; i < 4; ++i) {
          float vv = acc1[mt][nt][i] + bias;
          vv = 0.5f * vv * (1.0f + erff(vv * 0.70710678118654752440f));
          int lp = (4 * g + i) + 16 * ((nl >> 3) & 3);
          *(uint16_t*)(lds + 32768 + (mt * 8 + wv) * 1024 + lp * 16 + (nl & 7) * 2) = f2bf(vv);
        }
      }
    }
    __syncthreads();
    // GEMM2 partial: m1half [64][256] x W2half^T -> acc2 += ; wave owns 32 c
#pragma unroll
    for (int kt = 0; kt < 8; ++kt) {
      B8 a[4];
#pragma unroll
      for (int mt = 0; mt < 4; ++mt)
        a[mt].q = *(const uint4*)(lds + 32768 + (mt * 8 + kt) * 1024 + lane * 16);
#pragma unroll
      for (int nt = 0; nt < 2; ++nt) {
        B8 bfr;
        bfr.q = *(const uint4*)(w2f + (size_t)(((wv * 2 + nt) * 16 + half * 8 + kt) * 512) + lane * 8);
#pragma unroll
        for (int mt = 0; mt < 4; ++mt) acc2[mt][nt] = mfma16(a[mt], bfr, acc2[mt][nt]);
      }
    }
  }

  // ---- epilogue: out = x2 + mlp ------------------------------------------
#pragma unroll
  for (int nt = 0; nt < 2; ++nt) {
    int c = wv * 32 + 16 * nt + r;
    float bias = bm2[c];
#pragma unroll
    for (int mt = 0; mt < 4; ++mt) {
      int p0 = tokbase + 16 * mt + 4 * g;
      f32x4 res = *(const f32x4*)(outp + (size_t)c * 16384 + p0);
      f32x4 o;
#pragma unroll
      for (int i = 0; i < 4; ++i) o[i] = res[i] + acc2[mt][nt][i] + bias;
      *(f32x4*)(outp + (size_t)c * 16384 + p0) = o;
    }
  }
}

// ---------------------------------------------------------------------------
extern "C" void kernel_launch(void* const* d_in, const int* in_sizes, int n_in,
                              void* d_out, int out_size, void* d_ws, size_t ws_size,
                              hipStream_t stream) {
  (void)in_sizes; (void)n_in; (void)out_size; (void)ws_size;
  const float* x     = (const float*)d_in[0];
  const float* wqkv  = (const float*)d_in[1];
  const float* wproj = (const float*)d_in[2];
  const float* bproj = (const float*)d_in[3];
  const float* ln1g  = (const float*)d_in[4];
  const float* ln1b  = (const float*)d_in[5];
  const float* ln2g  = (const float*)d_in[6];
  const float* ln2b  = (const float*)d_in[7];
  const float* w1    = (const float*)d_in[8];
  const float* bm1   = (const float*)d_in[9];
  const float* w2    = (const float*)d_in[10];
  const float* bm2   = (const float*)d_in[11];
  uint16_t* wbf = (uint16_t*)d_ws;        // 524288 bf16 weights (frag-linear)
  uint16_t* osc = wbf + 524288;           // 512*16*8*512 = 33554432 bf16 O frags
  float* out = (float*)d_out;

  transformer_prep<<<2048, 256, 0, stream>>>(wqkv, wproj, w1, w2, wbf);
  transformer_k1<<<512, 512, 0, stream>>>(x, bproj, ln1g, ln1b, wbf, osc, out);
  transformer_k2<<<2048, 512, 0, stream>>>(ln2g, ln2b, wbf + 262144, wbf + 393216, bm1, bm2, out);
}

// Round 4
// 730.651 us; speedup vs baseline: 1.4359x; 1.4359x over previous
//
#include <hip/hip_runtime.h>
#include <stdint.h>
#include <math.h>

// LightweightTransformerLayer fused implementation for gfx950 (round 4).
// B=8, C=256, N=64, P=256; 512 sequences of [256 tokens x 256 ch].
//
// ROUND 4 CHANGE: __launch_bounds__(512,2) on k1/k2 (was (512,4)). The (512,4)
// bound capped the allocator at 128 VGPRs and it spilled hfrag (64 regs live)
// to scratch: VGPR_Count=64, +1.4GB HBM spill traffic, k1 746us. LDS already
// caps both kernels at 2 WG/CU, so the looser bound costs no occupancy.
//
// prep: fp32->bf16 weights into ws in FRAG-LINEAR layout (each 16x32 MFMA tile
//       = 64 contiguous uint4, one per lane) so every weight fragment load is a
//       fully coalesced 1KB global read (L1/L2-served). W_q pre-scaled by
//       SCALE*log2e for exp2-domain softmax.
// k1  : per-sequence WG (512 thr, 64KB LDS -> 2 WG/CU): LN1 from direct global
//       reads (no LDS), h in registers; per head: K/V gen -> LDS, Q gen, flash
//       attention (S^T = K Q^T trick, in-register shuffle transposes); O frags
//       spilled to global scratch (same-wave RAW only, no barriers); proj +
//       bias + residual -> x2 fp32 to d_out. 8 barriers total.
// k2  : per-64-token WG (512 thr, 67KB LDS -> 2 WG/CU): x2 -> LN2 (stats via
//       shfl + tiny LDS) -> h2 frags in LDS -> MLP1 + exact GELU -> m1 frags
//       (hidden dim halved, GEMM2 acc in regs across halves) -> MLP2 ->
//       residual RMW d_out.

#define DEV static __device__ __forceinline__

typedef __bf16 bf16x8 __attribute__((ext_vector_type(8)));
typedef float  f32x4  __attribute__((ext_vector_type(4)));

union B8 { bf16x8 v; uint4 q; uint32_t u[4]; uint16_t h[8]; };

DEV uint16_t f2bf(float f) {
  uint32_t u = __float_as_uint(f);
  return (uint16_t)((u + 0x7FFFu + ((u >> 16) & 1u)) >> 16);  // RNE
}
DEV float bf2f(uint16_t h) { return __uint_as_float(((uint32_t)h) << 16); }
DEV uint32_t pk2(float a, float b) { return (uint32_t)f2bf(a) | ((uint32_t)f2bf(b) << 16); }

DEV f32x4 mfma16(const B8& a, const B8& b, f32x4 c) {
  return __builtin_amdgcn_mfma_f32_16x16x32_bf16(a.v, b.v, c, 0, 0, 0);
}

DEV uint32_t shfl_u(uint32_t v, int src) { return (uint32_t)__shfl((int)v, src, 64); }

DEV B8 mk(const uint32_t* w) {
  B8 x; x.u[0] = w[0]; x.u[1] = w[1]; x.u[2] = w[2]; x.u[3] = w[3]; return x;
}

// Transpose C-frags (4 row-tiles of 16, regs packed as bf16 pairs pk0=(r0,r1),
// pk1=(r2,r3)) into an A/B-frag. Verified (round 1 passed end-to-end):
// C/D col=lane&15, row=(lane>>4)*4+i ; A/B idx=lane&15, k-octet=(lane>>4)*8.
DEV void xpose(const uint32_t* pk0, const uint32_t* pk1, int kd, int g, int r, uint32_t* out) {
  const int sA = 32 * (g & 1) + r;
  const int sB = sA + 16;
  const int tA = 2 * kd, tB = 2 * kd + 1;
  uint32_t a0 = shfl_u(pk0[tA], sA), b0 = shfl_u(pk0[tB], sA);
  uint32_t a1 = shfl_u(pk1[tA], sA), b1 = shfl_u(pk1[tB], sA);
  uint32_t a2 = shfl_u(pk0[tA], sB), b2 = shfl_u(pk0[tB], sB);
  uint32_t a3 = shfl_u(pk1[tA], sB), b3 = shfl_u(pk1[tB], sB);
  const bool hi = g >= 2;
  out[0] = hi ? b0 : a0;
  out[1] = hi ? b1 : a1;
  out[2] = hi ? b2 : a2;
  out[3] = hi ? b3 : a3;
}

// ---------------------------------------------------------------------------
// prep: weights -> bf16 FRAG-LINEAR. For a matrix [R][C] (row-major, C=in):
// tile (tr, tk) covers rows 16tr..+16, cols 32tk..+32; stored at
// (tr*(C/32)+tk)*512 + lane*8 + j  with lane = (row&15) + 16*((col>>3)&3),
// j = col&7.  Segments (bf16 elems): wqkv_f @0 (196608, first 65536 = W_q
// scaled), wproj_f @196608 (65536), w1_f @262144 (131072), w2_f @393216 (131072).
__global__ void transformer_prep(const float* __restrict__ wqkv,
                                 const float* __restrict__ wproj,
                                 const float* __restrict__ w1,
                                 const float* __restrict__ w2,
                                 uint16_t* __restrict__ dst) {
  int e = blockIdx.x * 256 + threadIdx.x;  // grid 2048*256 = 524288 exactly
  const float* src; int C, local;
  if (e < 196608)      { src = wqkv;  C = 256; local = e; }
  else if (e < 262144) { src = wproj; C = 256; local = e - 196608; }
  else if (e < 393216) { src = w1;    C = 256; local = e - 262144; }
  else                 { src = w2;    C = 512; local = e - 393216; }
  int k32 = C >> 5;
  int tile = local >> 9, within = local & 511;
  int ln = within >> 3, j = within & 7;
  int tr = tile / k32, tk = tile - tr * k32;
  int row = tr * 16 + (ln & 15), col = tk * 32 + (ln >> 4) * 8 + j;
  float v = src[row * C + col];
  if (e < 65536) v *= 0.18033688011112042f;  // SCALE * log2(e) folded into W_q
  dst[e] = f2bf(v);
}

// ---------------------------------------------------------------------------
// k1 LDS map (65536 B): K bf16 [q 256][d 64] pitch 128B @0 (32768),
//                       V^T bf16 [d 64][q 256] pitch 512B @32768 (32768).
// Row-major tiles swizzled: byte ^= (row&7)<<4.
__global__ __launch_bounds__(512, 2) void transformer_k1(
    const float* __restrict__ x,
    const float* __restrict__ bproj,
    const float* __restrict__ ln1g, const float* __restrict__ ln1b,
    const uint16_t* __restrict__ wf,      // wqkv_f @0, wproj_f @196608
    uint16_t* __restrict__ osc,           // O frag scratch, 64MB
    float* __restrict__ out) {
  __shared__ __attribute__((aligned(16))) uint8_t lds[65536];
  const int tid = threadIdx.x;
  const int lane = tid & 63;
  const int wv = tid >> 6;       // wave 0..7, owns token rows 32*wv..+32
  const int r = lane & 15;
  const int g = lane >> 4;
  const int s = blockIdx.x;      // sequence = b*64 + n
  const int bb = s >> 6, nn = s & 63;
  const float* xs = x + (size_t)bb * 4194304 + (size_t)nn * 256;  // (c,p) at c*16384+p
  float* outp = out + (size_t)bb * 4194304 + (size_t)nn * 256;
  const f32x4 fz = {0.f, 0.f, 0.f, 0.f};

  // ============ Phase 1: x -> LN1 -> h as register frags (no LDS) ===========
  // hfrag[rt][kt]: h[p = 32wv+16rt+r][c = 32kt+8g .. +8] as bf16x8.
  // Global loads: per inst 4 c-rows x 16 consecutive p = 4 full 64B sectors.
  uint32_t hfrag[2][8][4];
  float s1[2] = {0.f, 0.f}, s2[2] = {0.f, 0.f};
#pragma unroll
  for (int rt = 0; rt < 2; ++rt) {
    int p = 32 * wv + 16 * rt + r;
#pragma unroll
    for (int kt = 0; kt < 8; ++kt) {
      int c0 = 32 * kt + 8 * g;
      float v[8];
#pragma unroll
      for (int j = 0; j < 8; ++j) {
        v[j] = xs[(size_t)(c0 + j) * 16384 + p];
        s1[rt] += v[j];
        s2[rt] += v[j] * v[j];
      }
#pragma unroll
      for (int w = 0; w < 4; ++w) hfrag[rt][kt][w] = pk2(v[2 * w], v[2 * w + 1]);
    }
  }
  float mu[2], rs[2];
#pragma unroll
  for (int rt = 0; rt < 2; ++rt) {  // lanes r,r+16,r+32,r+48 share a token row
    float a = s1[rt]; a += __shfl_xor(a, 16, 64); a += __shfl_xor(a, 32, 64);
    float b = s2[rt]; b += __shfl_xor(b, 16, 64); b += __shfl_xor(b, 32, 64);
    mu[rt] = a * (1.0f / 256.0f);
    float var = b * (1.0f / 256.0f) - mu[rt] * mu[rt];
    rs[rt] = rsqrtf(var + 1e-5f);
  }
#pragma unroll
  for (int kt = 0; kt < 8; ++kt) {  // normalize in place
    int c0 = 32 * kt + 8 * g;
    f32x4 gA = *(const f32x4*)(ln1g + c0), gB = *(const f32x4*)(ln1g + c0 + 4);
    f32x4 bA = *(const f32x4*)(ln1b + c0), bB = *(const f32x4*)(ln1b + c0 + 4);
#pragma unroll
    for (int rt = 0; rt < 2; ++rt) {
#pragma unroll
      for (int w = 0; w < 4; ++w) {
        uint32_t pw = hfrag[rt][kt][w];
        float lo = bf2f((uint16_t)(pw & 0xFFFFu));
        float hi = bf2f((uint16_t)(pw >> 16));
        float glo = (w < 2) ? gA[2 * w] : gB[2 * w - 4];
        float ghi = (w < 2) ? gA[2 * w + 1] : gB[2 * w - 3];
        float blo = (w < 2) ? bA[2 * w] : bB[2 * w - 4];
        float bhi = (w < 2) ? bA[2 * w + 1] : bB[2 * w - 3];
        lo = (lo - mu[rt]) * rs[rt] * glo + blo;
        hi = (hi - mu[rt]) * rs[rt] * ghi + bhi;
        hfrag[rt][kt][w] = pk2(lo, hi);
      }
    }
  }

  // ============ Phase 2: attention heads ====================================
#pragma unroll 1
  for (int hd = 0; hd < 4; ++hd) {
    // ---- K (m=0) and V^T (m=1) generation; W frags straight from global
#pragma unroll
    for (int m = 0; m < 2; ++m) {
      f32x4 acc[2][4];
#pragma unroll
      for (int rt = 0; rt < 2; ++rt)
#pragma unroll
        for (int ct = 0; ct < 4; ++ct) acc[rt][ct] = fz;
#pragma unroll
      for (int kt = 0; kt < 8; ++kt) {
#pragma unroll
        for (int ct = 0; ct < 4; ++ct) {
          B8 wfr;
          wfr.q = *(const uint4*)(wf + (size_t)((((m + 1) * 16 + hd * 4 + ct) * 8 + kt) * 512) + lane * 8);
#pragma unroll
          for (int rt = 0; rt < 2; ++rt) {
            B8 a = mk(hfrag[rt][kt]);
            acc[rt][ct] = mfma16(a, wfr, acc[rt][ct]);
          }
        }
      }
#pragma unroll
      for (int rt = 0; rt < 2; ++rt) {
#pragma unroll
        for (int ct = 0; ct < 4; ++ct) {
          int d = 16 * ct + r;
          int q0 = 32 * wv + 16 * rt + 4 * g;
          if (m == 0) {  // K[q][d], pitch 128B
#pragma unroll
            for (int i = 0; i < 4; ++i) {
              int qq = q0 + i;
              *(uint16_t*)(lds + ((qq * 128 + d * 2) ^ ((qq & 7) << 4))) = f2bf(acc[rt][ct][i]);
            }
          } else {       // V^T[d][q], pitch 512B, 4 consecutive q packed
            uint2 pv;
            pv.x = pk2(acc[rt][ct][0], acc[rt][ct][1]);
            pv.y = pk2(acc[rt][ct][2], acc[rt][ct][3]);
            *(uint2*)(lds + ((32768 + d * 512 + q0 * 2) ^ ((d & 7) << 4))) = pv;
          }
        }
      }
    }
    __syncthreads();  // K/V visible (also: prior flash reads done before write)

    // ---- flash attention; pt-sequential (2 x 16 query rows) to cap VGPRs
#pragma unroll 1
    for (int pt = 0; pt < 2; ++pt) {
      // Q^T[d 64][p 16] = (scaled Wq) x h ; Wq frags from global
      f32x4 qT[4];
#pragma unroll
      for (int mt = 0; mt < 4; ++mt) qT[mt] = fz;
#pragma unroll
      for (int kt = 0; kt < 8; ++kt) {
        B8 hb = mk(hfrag[pt][kt]);
#pragma unroll
        for (int mt = 0; mt < 4; ++mt) {
          B8 wa;
          wa.q = *(const uint4*)(wf + (size_t)(((hd * 4 + mt) * 8 + kt) * 512) + lane * 8);
          qT[mt] = mfma16(wa, hb, qT[mt]);
        }
      }
      uint32_t pq0[4], pq1[4];
#pragma unroll
      for (int mt = 0; mt < 4; ++mt) {
        pq0[mt] = pk2(qT[mt][0], qT[mt][1]);
        pq1[mt] = pk2(qT[mt][2], qT[mt][3]);
      }
      uint32_t qb[2][4];
#pragma unroll
      for (int kd = 0; kd < 2; ++kd) xpose(pq0, pq1, kd, g, r, qb[kd]);

      float m_ = -1e30f, l_ = 0.f;
      f32x4 oT[4];
#pragma unroll
      for (int dt = 0; dt < 4; ++dt) oT[dt] = fz;

#pragma unroll 1
      for (int chk = 0; chk < 4; ++chk) {  // 64 keys per step
        f32x4 sT[4];
#pragma unroll
        for (int qt = 0; qt < 4; ++qt) sT[qt] = fz;
#pragma unroll
        for (int kd = 0; kd < 2; ++kd) {
          B8 qf = mk(qb[kd]);
#pragma unroll
          for (int qt = 0; qt < 4; ++qt) {
            int qq = chk * 64 + 16 * qt + r;
            B8 ka;
            ka.q = *(const uint4*)(lds + ((qq * 128 + (32 * kd + 8 * g) * 2) ^ ((qq & 7) << 4)));
            sT[qt] = mfma16(ka, qf, sT[qt]);  // S^T[q][p], log2-domain
          }
        }
        // online softmax over q (16 in-lane values + g-butterfly)
        float tmax = sT[0][0];
#pragma unroll
        for (int qt = 0; qt < 4; ++qt)
#pragma unroll
          for (int i = 0; i < 4; ++i) tmax = fmaxf(tmax, sT[qt][i]);
        tmax = fmaxf(tmax, __shfl_xor(tmax, 16, 64));
        tmax = fmaxf(tmax, __shfl_xor(tmax, 32, 64));
        float mn = fmaxf(m_, tmax);
        float fcor = exp2f(m_ - mn);
        float ts = 0.f;
#pragma unroll
        for (int qt = 0; qt < 4; ++qt)
#pragma unroll
          for (int i = 0; i < 4; ++i) {
            float e = exp2f(sT[qt][i] - mn);
            sT[qt][i] = e;
            ts += e;
          }
        ts += __shfl_xor(ts, 16, 64);
        ts += __shfl_xor(ts, 32, 64);
        l_ = l_ * fcor + ts;
        m_ = mn;
#pragma unroll
        for (int dt = 0; dt < 4; ++dt)
#pragma unroll
          for (int i = 0; i < 4; ++i) oT[dt][i] *= fcor;
        // P^T C-frags -> PV B-frags (in-register shuffle transpose)
        uint32_t pp0[4], pp1[4];
#pragma unroll
        for (int qt = 0; qt < 4; ++qt) {
          pp0[qt] = pk2(sT[qt][0], sT[qt][1]);
          pp1[qt] = pk2(sT[qt][2], sT[qt][3]);
        }
#pragma unroll
        for (int qk = 0; qk < 2; ++qk) {
          uint32_t pb[4];
          xpose(pp0, pp1, qk, g, r, pb);
          B8 pf = mk(pb);
#pragma unroll
          for (int dt = 0; dt < 4; ++dt) {
            B8 va;
            va.q = *(const uint4*)(lds + ((32768 + (16 * dt + r) * 512 + (chk * 64 + 32 * qk + 8 * g) * 2) ^ ((r & 7) << 4)));
            oT[dt] = mfma16(va, pf, oT[dt]);  // O^T[d][p]
          }
        }
      }
      float inv = 1.0f / l_;
      uint32_t po0[4], po1[4];
#pragma unroll
      for (int dt = 0; dt < 4; ++dt) {
        po0[dt] = pk2(oT[dt][0] * inv, oT[dt][1] * inv);
        po1[dt] = pk2(oT[dt][2] * inv, oT[dt][3] * inv);
      }
      // O as proj A-frags -> global scratch (same-wave RAW only, coalesced 1KB)
#pragma unroll
      for (int kd = 0; kd < 2; ++kd) {
        uint32_t ofr[4];
        xpose(po0, po1, kd, g, r, ofr);
        B8 t; t.u[0] = ofr[0]; t.u[1] = ofr[1]; t.u[2] = ofr[2]; t.u[3] = ofr[3];
        *(uint4*)(osc + (size_t)((s * 16 + 2 * wv + pt) * 8 + 2 * hd + kd) * 512 + lane * 8) = t.q;
      }
    }
    __syncthreads();  // flash K/V reads done before next head overwrites
  }

  // ============ Phase 3: proj + bias + residual -> x2 fp32 (d_out) ==========
  // No LDS, no barriers: A-frags from osc (own wave's), W frags from global.
#pragma unroll 1
  for (int q3 = 0; q3 < 4; ++q3) {  // 64 output channels per step
    f32x4 acc[2][4];
#pragma unroll
    for (int rt = 0; rt < 2; ++rt)
#pragma unroll
      for (int ct = 0; ct < 4; ++ct) acc[rt][ct] = fz;
#pragma unroll
    for (int kt = 0; kt < 8; ++kt) {
      B8 a[2];
#pragma unroll
      for (int rt = 0; rt < 2; ++rt)
        a[rt].q = *(const uint4*)(osc + (size_t)((s * 16 + 2 * wv + rt) * 8 + kt) * 512 + lane * 8);
#pragma unroll
      for (int ct = 0; ct < 4; ++ct) {
        B8 wfr;
        wfr.q = *(const uint4*)(wf + 196608 + (size_t)(((q3 * 4 + ct) * 8 + kt) * 512) + lane * 8);
#pragma unroll
        for (int rt = 0; rt < 2; ++rt) acc[rt][ct] = mfma16(a[rt], wfr, acc[rt][ct]);
      }
    }
#pragma unroll
    for (int rt = 0; rt < 2; ++rt) {
#pragma unroll
      for (int ct = 0; ct < 4; ++ct) {
        int c = q3 * 64 + 16 * ct + r;
        float bias = bproj[c];
        int p0 = 32 * wv + 16 * rt + 4 * g;
        f32x4 res = *(const f32x4*)(xs + (size_t)c * 16384 + p0);
        f32x4 x2v;
#pragma unroll
        for (int i = 0; i < 4; ++i) x2v[i] = acc[rt][ct][i] + bias + res[i];
        *(f32x4*)(outp + (size_t)c * 16384 + p0) = x2v;
      }
    }
  }
}

// ---------------------------------------------------------------------------
// k2: LN2 + MLP + residual. WG = (sequence s, 64-token group tg).
// LDS (68608 B): h2 frags 32KB @0, m1 frags (per hidden-half) 32KB @32768,
//                stat partials @65536 (1KB), mu/rs @66560 (512B).
__global__ __launch_bounds__(512, 2) void transformer_k2(
    const float* __restrict__ ln2g, const float* __restrict__ ln2b,
    const uint16_t* __restrict__ w1f, const uint16_t* __restrict__ w2f,
    const float* __restrict__ bm1, const float* __restrict__ bm2,
    float* __restrict__ out) {
  __shared__ __attribute__((aligned(16))) uint8_t lds[68608];
  const int tid = threadIdx.x;
  const int lane = tid & 63;
  const int wv = tid >> 6;
  const int r = lane & 15, g = lane >> 4;
  const int bid = blockIdx.x;
  const int s = bid >> 2, tg = bid & 3;
  const int bb = s >> 6, nn = s & 63;
  float* outp = out + (size_t)bb * 4194304 + (size_t)nn * 256;
  const int tokbase = tg * 64;
  const f32x4 fz = {0.f, 0.f, 0.f, 0.f};
  const int mtw = wv & 3, kth = wv >> 2;      // wave -> (row-tile, c-half)
  const int p = tokbase + 16 * mtw + r;       // this lane's token

  // ---- read x2 slice (kept in regs), accumulate LN2 partial stats ----------
  float v[4][8];
  float s1 = 0.f, s2 = 0.f;
#pragma unroll
  for (int k2l = 0; k2l < 4; ++k2l) {
    int c0 = (kth * 4 + k2l) * 32 + 8 * g;
#pragma unroll
    for (int j = 0; j < 8; ++j) {
      float t = outp[(size_t)(c0 + j) * 16384 + p];
      v[k2l][j] = t;
      s1 += t;
      s2 += t * t;
    }
  }
  s1 += __shfl_xor(s1, 16, 64); s1 += __shfl_xor(s1, 32, 64);
  s2 += __shfl_xor(s2, 16, 64); s2 += __shfl_xor(s2, 32, 64);
  if (g == 0) {  // partial over this wave-half's 128 channels
    float2 pr; pr.x = s1; pr.y = s2;
    *(float2*)(lds + 65536 + ((16 * mtw + r) * 2 + kth) * 8) = pr;
  }
  __syncthreads();
  if (tid < 64) {
    float2 a = *(const float2*)(lds + 65536 + (tid * 2 + 0) * 8);
    float2 b = *(const float2*)(lds + 65536 + (tid * 2 + 1) * 8);
    float su = a.x + b.x, sq = a.y + b.y;
    float m = su * (1.0f / 256.0f);
    float var = sq * (1.0f / 256.0f) - m * m;
    float2 st; st.x = m; st.y = rsqrtf(var + 1e-5f);
    *(float2*)(lds + 66560 + tid * 8) = st;
  }
  __syncthreads();
  float2 st = *(const float2*)(lds + 66560 + (16 * mtw + r) * 8);
  // ---- normalize + pack h2 frags into LDS (frag-linear, conflict-free) -----
#pragma unroll
  for (int k2l = 0; k2l < 4; ++k2l) {
    int kt = kth * 4 + k2l;
    int c0 = kt * 32 + 8 * g;
    f32x4 gA = *(const f32x4*)(ln2g + c0), gB = *(const f32x4*)(ln2g + c0 + 4);
    f32x4 bA = *(const f32x4*)(ln2b + c0), bB = *(const f32x4*)(ln2b + c0 + 4);
    float nv[8];
#pragma unroll
    for (int j = 0; j < 8; ++j) {
      float gg = (j < 4) ? gA[j] : gB[j - 4];
      float bb2 = (j < 4) ? bA[j] : bB[j - 4];
      nv[j] = (v[k2l][j] - st.x) * st.y * gg + bb2;
    }
    B8 t;
#pragma unroll
    for (int w = 0; w < 4; ++w) t.u[w] = pk2(nv[2 * w], nv[2 * w + 1]);
    *(uint4*)(lds + (mtw * 8 + kt) * 1024 + lane * 16) = t.q;
  }
  __syncthreads();

  // ---- MLP: hidden dim in 2 halves; GEMM2 accumulates in regs across halves
  f32x4 acc2[4][2];
#pragma unroll
  for (int mt = 0; mt < 4; ++mt)
#pragma unroll
    for (int nt = 0; nt < 2; ++nt) acc2[mt][nt] = fz;

#pragma unroll 1
  for (int half = 0; half < 2; ++half) {
    // GEMM1: [64 tok][256 c] x W1half^T -> wave owns 32 hidden cols
    f32x4 acc1[4][2];
#pragma unroll
    for (int mt = 0; mt < 4; ++mt)
#pragma unroll
      for (int nt = 0; nt < 2; ++nt) acc1[mt][nt] = fz;
#pragma unroll
    for (int kt = 0; kt < 8; ++kt) {
      B8 a[4];
#pragma unroll
      for (int mt = 0; mt < 4; ++mt)
        a[mt].q = *(const uint4*)(lds + (mt * 8 + kt) * 1024 + lane * 16);
#pragma unroll
      for (int nt = 0; nt < 2; ++nt) {
        B8 bfr;
        bfr.q = *(const uint4*)(w1f + (size_t)((((half * 16 + wv * 2 + nt) * 8) + kt) * 512) + lane * 8);
#pragma unroll
        for (int mt = 0; mt < 4; ++mt) acc1[mt][nt] = mfma16(a[mt], bfr, acc1[mt][nt]);
      }
    }
    if (half) __syncthreads();  // GEMM2(half0) m1 reads done before overwrite
    // bias + exact GELU + scatter m1 C-frags into A-frag-linear LDS
#pragma unroll
    for (int nt = 0; nt < 2; ++nt) {
      int nl = wv * 32 + 16 * nt + r;        // hidden index within half
      float bias = bm1[half * 256 + nl];
#pragma unroll
      for (int mt = 0; mt < 4; ++mt) {
#pragma unroll
        for (int i = 0; i < 4; ++i) {
          float vv = acc1[mt][nt][i] + bias;
          vv = 0.5f * vv * (1.0f + erff(vv * 0.70710678118654752440f));
          int lp = (4 * g + i) + 16 * ((nl >> 3) & 3);
          *(uint16_t*)(lds + 32768 + (mt * 8 + wv) * 1024 + lp * 16 + (nl & 7) * 2) = f2bf(vv);
        }
      }
    }
    __syncthreads();
    // GEMM2 partial: m1half [64][256] x W2half^T -> acc2 += ; wave owns 32 c
#pragma unroll
    for (int kt = 0; kt < 8; ++kt) {
      B8 a[4];
#pragma unroll
      for (int mt = 0; mt < 4; ++mt)
        a[mt].q = *(const uint4*)(lds + 32768 + (mt * 8 + kt) * 1024 + lane * 16);
#pragma unroll
      for (int nt = 0; nt < 2; ++nt) {
        B8 bfr;
        bfr.q = *(const uint4*)(w2f + (size_t)(((wv * 2 + nt) * 16 + half * 8 + kt) * 512) + lane * 8);
#pragma unroll
        for (int mt = 0; mt < 4; ++mt) acc2[mt][nt] = mfma16(a[mt], bfr, acc2[mt][nt]);
      }
    }
  }

  // ---- epilogue: out = x2 + mlp ------------------------------------------
#pragma unroll
  for (int nt = 0; nt < 2; ++nt) {
    int c = wv * 32 + 16 * nt + r;
    float bias = bm2[c];
#pragma unroll
    for (int mt = 0; mt < 4; ++mt) {
      int p0 = tokbase + 16 * mt + 4 * g;
      f32x4 res = *(const f32x4*)(outp + (size_t)c * 16384 + p0);
      f32x4 o;
#pragma unroll
      for (int i = 0; i < 4; ++i) o[i] = res[i] + acc2[mt][nt][i] + bias;
      *(f32x4*)(outp + (size_t)c * 16384 + p0) = o;
    }
  }
}

// ---------------------------------------------------------------------------
extern "C" void kernel_launch(void* const* d_in, const int* in_sizes, int n_in,
                              void* d_out, int out_size, void* d_ws, size_t ws_size,
                              hipStream_t stream) {
  (void)in_sizes; (void)n_in; (void)out_size; (void)ws_size;
  const float* x     = (const float*)d_in[0];
  const float* wqkv  = (const float*)d_in[1];
  const float* wproj = (const float*)d_in[2];
  const float* bproj = (const float*)d_in[3];
  const float* ln1g  = (const float*)d_in[4];
  const float* ln1b  = (const float*)d_in[5];
  const float* ln2g  = (const float*)d_in[6];
  const float* ln2b  = (const float*)d_in[7];
  const float* w1    = (const float*)d_in[8];
  const float* bm1   = (const float*)d_in[9];
  const float* w2    = (const float*)d_in[10];
  const float* bm2   = (const float*)d_in[11];
  uint16_t* wbf = (uint16_t*)d_ws;        // 524288 bf16 weights (frag-linear)
  uint16_t* osc = wbf + 524288;           // 512*16*8*512 = 33554432 bf16 O frags
  float* out = (float*)d_out;

  transformer_prep<<<2048, 256, 0, stream>>>(wqkv, wproj, w1, w2, wbf);
  transformer_k1<<<512, 512, 0, stream>>>(x, bproj, ln1g, ln1b, wbf, osc, out);
  transformer_k2<<<2048, 512, 0, stream>>>(ln2g, ln2b, wbf + 262144, wbf + 393216, bm1, bm2, out);
}

// Round 5
// 710.481 us; speedup vs baseline: 1.4766x; 1.0284x over previous
//
#include <hip/hip_runtime.h>
#include <stdint.h>
#include <math.h>

// LightweightTransformerLayer fused implementation for gfx950 (round 5).
// B=8, C=256, N=64, P=256; 512 sequences of [256 tokens x 256 ch].
//
// ROUND 5 CHANGE: 1024-thread / 16-wave WGs, per-wave state halved.
// Round-4 evidence: VGPR_Count=128 (arch) + ~32-48 live AGPRs (unified file)
// -> ~160 total/wave -> 3 waves/SIMD -> second 512-thr WG can't co-reside
// (Occupancy 22.7%). With 16 waves/WG and wave-owned token count halved
// (hfrag 64->32 regs), total regs fit the 128 cap for 4 waves/SIMD -> 50%
// occupancy ceiling from one WG.
//
// prep: fp32->bf16 weights in FRAG-LINEAR layout (16x32 MFMA tile = 64
//       contiguous uint4) -> every weight fragment load is a coalesced 1KB
//       global read. W_q pre-scaled by SCALE*log2e.
// k1  : per-sequence WG (1024 thr, 64KB LDS): LN1 direct from global, h in
//       regs (1 tile/wave); per head: K/V gen -> LDS, Q gen, flash attn
//       (S^T = K Q^T, in-register shuffle transposes); O frags to global
//       scratch (same-wave RAW); proj + bias + residual -> x2 fp32 to d_out.
// k2  : per-64-token WG (1024 thr, 104KB LDS): x2 -> LN2 (LDS partials +
//       redundant all-wave reduce) -> h2 frags LDS -> MLP1 + exact GELU ->
//       m1 frags (full 512 hidden) -> MLP2 -> residual RMW d_out. 3 barriers.

#define DEV static __device__ __forceinline__

typedef __bf16 bf16x8 __attribute__((ext_vector_type(8)));
typedef float  f32x4  __attribute__((ext_vector_type(4)));

union B8 { bf16x8 v; uint4 q; uint32_t u[4]; uint16_t h[8]; };

DEV uint16_t f2bf(float f) {
  uint32_t u = __float_as_uint(f);
  return (uint16_t)((u + 0x7FFFu + ((u >> 16) & 1u)) >> 16);  // RNE
}
DEV float bf2f(uint16_t h) { return __uint_as_float(((uint32_t)h) << 16); }
DEV uint32_t pk2(float a, float b) { return (uint32_t)f2bf(a) | ((uint32_t)f2bf(b) << 16); }

DEV f32x4 mfma16(const B8& a, const B8& b, f32x4 c) {
  return __builtin_amdgcn_mfma_f32_16x16x32_bf16(a.v, b.v, c, 0, 0, 0);
}

DEV uint32_t shfl_u(uint32_t v, int src) { return (uint32_t)__shfl((int)v, src, 64); }

DEV B8 mk(const uint32_t* w) {
  B8 x; x.u[0] = w[0]; x.u[1] = w[1]; x.u[2] = w[2]; x.u[3] = w[3]; return x;
}

// Transpose C-frags (4 row-tiles of 16, regs packed as bf16 pairs pk0=(r0,r1),
// pk1=(r2,r3)) into an A/B-frag. Verified end-to-end rounds 1-4:
// C/D col=lane&15, row=(lane>>4)*4+i ; A/B idx=lane&15, k-octet=(lane>>4)*8.
DEV void xpose(const uint32_t* pk0, const uint32_t* pk1, int kd, int g, int r, uint32_t* out) {
  const int sA = 32 * (g & 1) + r;
  const int sB = sA + 16;
  const int tA = 2 * kd, tB = 2 * kd + 1;
  uint32_t a0 = shfl_u(pk0[tA], sA), b0 = shfl_u(pk0[tB], sA);
  uint32_t a1 = shfl_u(pk1[tA], sA), b1 = shfl_u(pk1[tB], sA);
  uint32_t a2 = shfl_u(pk0[tA], sB), b2 = shfl_u(pk0[tB], sB);
  uint32_t a3 = shfl_u(pk1[tA], sB), b3 = shfl_u(pk1[tB], sB);
  const bool hi = g >= 2;
  out[0] = hi ? b0 : a0;
  out[1] = hi ? b1 : a1;
  out[2] = hi ? b2 : a2;
  out[3] = hi ? b3 : a3;
}

// ---------------------------------------------------------------------------
// prep: weights -> bf16 FRAG-LINEAR. For a matrix [R][C] (row-major, C=in):
// tile (tr, tk) covers rows 16tr..+16, cols 32tk..+32; stored at
// (tr*(C/32)+tk)*512 + lane*8 + j  with lane = (row&15) + 16*((col>>3)&3),
// j = col&7.  Segments (bf16 elems): wqkv_f @0 (196608, first 65536 = W_q
// scaled), wproj_f @196608 (65536), w1_f @262144 (131072), w2_f @393216 (131072).
__global__ void transformer_prep(const float* __restrict__ wqkv,
                                 const float* __restrict__ wproj,
                                 const float* __restrict__ w1,
                                 const float* __restrict__ w2,
                                 uint16_t* __restrict__ dst) {
  int e = blockIdx.x * 256 + threadIdx.x;  // grid 2048*256 = 524288 exactly
  const float* src; int C, local;
  if (e < 196608)      { src = wqkv;  C = 256; local = e; }
  else if (e < 262144) { src = wproj; C = 256; local = e - 196608; }
  else if (e < 393216) { src = w1;    C = 256; local = e - 262144; }
  else                 { src = w2;    C = 512; local = e - 393216; }
  int k32 = C >> 5;
  int tile = local >> 9, within = local & 511;
  int ln = within >> 3, j = within & 7;
  int tr = tile / k32, tk = tile - tr * k32;
  int row = tr * 16 + (ln & 15), col = tk * 32 + (ln >> 4) * 8 + j;
  float v = src[row * C + col];
  if (e < 65536) v *= 0.18033688011112042f;  // SCALE * log2(e) folded into W_q
  dst[e] = f2bf(v);
}

// ---------------------------------------------------------------------------
// k1 LDS map (65536 B): K bf16 [q 256][d 64] pitch 128B @0 (32768),
//                       V^T bf16 [d 64][q 256] pitch 512B @32768 (32768).
// Row-major tiles swizzled: byte ^= (row&7)<<4.
__global__ __launch_bounds__(1024, 4) void transformer_k1(
    const float* __restrict__ x,
    const float* __restrict__ bproj,
    const float* __restrict__ ln1g, const float* __restrict__ ln1b,
    const uint16_t* __restrict__ wf,      // wqkv_f @0, wproj_f @196608
    uint16_t* __restrict__ osc,           // O frag scratch, 64MB
    float* __restrict__ out) {
  __shared__ __attribute__((aligned(16))) uint8_t lds[65536];
  const int tid = threadIdx.x;
  const int lane = tid & 63;
  const int w = tid >> 6;        // wave 0..15, owns token rows 16w..+15
  const int r = lane & 15;
  const int g = lane >> 4;
  const int s = blockIdx.x;      // sequence = b*64 + n
  const int bb = s >> 6, nn = s & 63;
  const float* xs = x + (size_t)bb * 4194304 + (size_t)nn * 256;  // (c,p) at c*16384+p
  float* outp = out + (size_t)bb * 4194304 + (size_t)nn * 256;
  const f32x4 fz = {0.f, 0.f, 0.f, 0.f};

  // ============ Phase 1: x -> LN1 -> h as register frags (no LDS) ===========
  // hfrag[kt]: h[p = 16w+r][c = 32kt+8g .. +8] as bf16x8.
  uint32_t hfrag[8][4];
  {
    float s1 = 0.f, s2 = 0.f;
    const int p = 16 * w + r;
#pragma unroll
    for (int kt = 0; kt < 8; ++kt) {
      int c0 = 32 * kt + 8 * g;
      float v[8];
#pragma unroll
      for (int j = 0; j < 8; ++j) {
        v[j] = xs[(size_t)(c0 + j) * 16384 + p];
        s1 += v[j];
        s2 += v[j] * v[j];
      }
#pragma unroll
      for (int q = 0; q < 4; ++q) hfrag[kt][q] = pk2(v[2 * q], v[2 * q + 1]);
    }
    s1 += __shfl_xor(s1, 16, 64); s1 += __shfl_xor(s1, 32, 64);
    s2 += __shfl_xor(s2, 16, 64); s2 += __shfl_xor(s2, 32, 64);
    float mu = s1 * (1.0f / 256.0f);
    float var = s2 * (1.0f / 256.0f) - mu * mu;
    float rs = rsqrtf(var + 1e-5f);
#pragma unroll
    for (int kt = 0; kt < 8; ++kt) {
      int c0 = 32 * kt + 8 * g;
      f32x4 gA = *(const f32x4*)(ln1g + c0), gB = *(const f32x4*)(ln1g + c0 + 4);
      f32x4 bA = *(const f32x4*)(ln1b + c0), bB = *(const f32x4*)(ln1b + c0 + 4);
#pragma unroll
      for (int q = 0; q < 4; ++q) {
        uint32_t pw = hfrag[kt][q];
        float lo = bf2f((uint16_t)(pw & 0xFFFFu));
        float hi = bf2f((uint16_t)(pw >> 16));
        float glo = (q < 2) ? gA[2 * q] : gB[2 * q - 4];
        float ghi = (q < 2) ? gA[2 * q + 1] : gB[2 * q - 3];
        float blo = (q < 2) ? bA[2 * q] : bB[2 * q - 4];
        float bhi = (q < 2) ? bA[2 * q + 1] : bB[2 * q - 3];
        lo = (lo - mu) * rs * glo + blo;
        hi = (hi - mu) * rs * ghi + bhi;
        hfrag[kt][q] = pk2(lo, hi);
      }
    }
  }

  // ============ Phase 2: attention heads ====================================
#pragma unroll 1
  for (int hd = 0; hd < 4; ++hd) {
    // ---- K (m=0) and V^T (m=1) generation; wave computes its own 16 rows
#pragma unroll
    for (int m = 0; m < 2; ++m) {
      f32x4 acc[4];
#pragma unroll
      for (int ct = 0; ct < 4; ++ct) acc[ct] = fz;
#pragma unroll
      for (int kt = 0; kt < 8; ++kt) {
        B8 a = mk(hfrag[kt]);
#pragma unroll
        for (int ct = 0; ct < 4; ++ct) {
          B8 wfr;
          wfr.q = *(const uint4*)(wf + (size_t)((((m + 1) * 16 + hd * 4 + ct) * 8 + kt) * 512) + lane * 8);
          acc[ct] = mfma16(a, wfr, acc[ct]);
        }
      }
#pragma unroll
      for (int ct = 0; ct < 4; ++ct) {
        int d = 16 * ct + r;
        int q0 = 16 * w + 4 * g;
        if (m == 0) {  // K[q][d], pitch 128B
#pragma unroll
          for (int i = 0; i < 4; ++i) {
            int qq = q0 + i;
            *(uint16_t*)(lds + ((qq * 128 + d * 2) ^ ((qq & 7) << 4))) = f2bf(acc[ct][i]);
          }
        } else {       // V^T[d][q], pitch 512B, 4 consecutive q packed
          uint2 pv;
          pv.x = pk2(acc[ct][0], acc[ct][1]);
          pv.y = pk2(acc[ct][2], acc[ct][3]);
          *(uint2*)(lds + ((32768 + d * 512 + q0 * 2) ^ ((d & 7) << 4))) = pv;
        }
      }
    }
    __syncthreads();  // K/V visible (also: prior flash reads done before write)

    // ---- flash attention over the wave's own 16 queries
    {
      // Q^T[d 64][p 16] = (scaled Wq) x h ; Wq frags from global
      f32x4 qT[4];
#pragma unroll
      for (int mt = 0; mt < 4; ++mt) qT[mt] = fz;
#pragma unroll
      for (int kt = 0; kt < 8; ++kt) {
        B8 hb = mk(hfrag[kt]);
#pragma unroll
        for (int mt = 0; mt < 4; ++mt) {
          B8 wa;
          wa.q = *(const uint4*)(wf + (size_t)(((hd * 4 + mt) * 8 + kt) * 512) + lane * 8);
          qT[mt] = mfma16(wa, hb, qT[mt]);
        }
      }
      uint32_t pq0[4], pq1[4];
#pragma unroll
      for (int mt = 0; mt < 4; ++mt) {
        pq0[mt] = pk2(qT[mt][0], qT[mt][1]);
        pq1[mt] = pk2(qT[mt][2], qT[mt][3]);
      }
      uint32_t qb[2][4];
#pragma unroll
      for (int kd = 0; kd < 2; ++kd) xpose(pq0, pq1, kd, g, r, qb[kd]);

      float m_ = -1e30f, l_ = 0.f;
      f32x4 oT[4];
#pragma unroll
      for (int dt = 0; dt < 4; ++dt) oT[dt] = fz;

#pragma unroll 1
      for (int chk = 0; chk < 4; ++chk) {  // 64 keys per step
        f32x4 sT[4];
#pragma unroll
        for (int qt = 0; qt < 4; ++qt) sT[qt] = fz;
#pragma unroll
        for (int kd = 0; kd < 2; ++kd) {
          B8 qf = mk(qb[kd]);
#pragma unroll
          for (int qt = 0; qt < 4; ++qt) {
            int qq = chk * 64 + 16 * qt + r;
            B8 ka;
            ka.q = *(const uint4*)(lds + ((qq * 128 + (32 * kd + 8 * g) * 2) ^ ((qq & 7) << 4)));
            sT[qt] = mfma16(ka, qf, sT[qt]);  // S^T[key][query], log2-domain
          }
        }
        // online softmax over keys (16 in-lane values + g-butterfly)
        float tmax = sT[0][0];
#pragma unroll
        for (int qt = 0; qt < 4; ++qt)
#pragma unroll
          for (int i = 0; i < 4; ++i) tmax = fmaxf(tmax, sT[qt][i]);
        tmax = fmaxf(tmax, __shfl_xor(tmax, 16, 64));
        tmax = fmaxf(tmax, __shfl_xor(tmax, 32, 64));
        float mn = fmaxf(m_, tmax);
        float fcor = exp2f(m_ - mn);
        float ts = 0.f;
#pragma unroll
        for (int qt = 0; qt < 4; ++qt)
#pragma unroll
          for (int i = 0; i < 4; ++i) {
            float e = exp2f(sT[qt][i] - mn);
            sT[qt][i] = e;
            ts += e;
          }
        ts += __shfl_xor(ts, 16, 64);
        ts += __shfl_xor(ts, 32, 64);
        l_ = l_ * fcor + ts;
        m_ = mn;
#pragma unroll
        for (int dt = 0; dt < 4; ++dt)
#pragma unroll
          for (int i = 0; i < 4; ++i) oT[dt][i] *= fcor;
        // P^T C-frags -> PV B-frags (in-register shuffle transpose)
        uint32_t pp0[4], pp1[4];
#pragma unroll
        for (int qt = 0; qt < 4; ++qt) {
          pp0[qt] = pk2(sT[qt][0], sT[qt][1]);
          pp1[qt] = pk2(sT[qt][2], sT[qt][3]);
        }
#pragma unroll
        for (int qk = 0; qk < 2; ++qk) {
          uint32_t pb[4];
          xpose(pp0, pp1, qk, g, r, pb);
          B8 pf = mk(pb);
#pragma unroll
          for (int dt = 0; dt < 4; ++dt) {
            B8 va;
            va.q = *(const uint4*)(lds + ((32768 + (16 * dt + r) * 512 + (chk * 64 + 32 * qk + 8 * g) * 2) ^ ((r & 7) << 4)));
            oT[dt] = mfma16(va, pf, oT[dt]);  // O^T[d][query]
          }
        }
      }
      float inv = 1.0f / l_;
      uint32_t po0[4], po1[4];
#pragma unroll
      for (int dt = 0; dt < 4; ++dt) {
        po0[dt] = pk2(oT[dt][0] * inv, oT[dt][1] * inv);
        po1[dt] = pk2(oT[dt][2] * inv, oT[dt][3] * inv);
      }
      // O as proj A-frags -> global scratch (same-wave RAW only, coalesced 1KB)
#pragma unroll
      for (int kd = 0; kd < 2; ++kd) {
        uint32_t ofr[4];
        xpose(po0, po1, kd, g, r, ofr);
        B8 t; t.u[0] = ofr[0]; t.u[1] = ofr[1]; t.u[2] = ofr[2]; t.u[3] = ofr[3];
        *(uint4*)(osc + (size_t)((s * 16 + w) * 8 + 2 * hd + kd) * 512 + lane * 8) = t.q;
      }
    }
    __syncthreads();  // flash K/V reads done before next head overwrites
  }

  // ============ Phase 3: proj + bias + residual -> x2 fp32 (d_out) ==========
  // No LDS, no barriers: A-frags from osc (own wave's), W frags from global.
#pragma unroll 1
  for (int q3 = 0; q3 < 4; ++q3) {  // 64 output channels per step
    f32x4 acc[4];
#pragma unroll
    for (int ct = 0; ct < 4; ++ct) acc[ct] = fz;
#pragma unroll
    for (int kt = 0; kt < 8; ++kt) {
      B8 a;
      a.q = *(const uint4*)(osc + (size_t)((s * 16 + w) * 8 + kt) * 512 + lane * 8);
#pragma unroll
      for (int ct = 0; ct < 4; ++ct) {
        B8 wfr;
        wfr.q = *(const uint4*)(wf + 196608 + (size_t)(((q3 * 4 + ct) * 8 + kt) * 512) + lane * 8);
        acc[ct] = mfma16(a, wfr, acc[ct]);
      }
    }
#pragma unroll
    for (int ct = 0; ct < 4; ++ct) {
      int c = q3 * 64 + 16 * ct + r;
      float bias = bproj[c];
      int p0 = 16 * w + 4 * g;
      f32x4 res = *(const f32x4*)(xs + (size_t)c * 16384 + p0);
      f32x4 x2v;
#pragma unroll
      for (int i = 0; i < 4; ++i) x2v[i] = acc[ct][i] + bias + res[i];
      *(f32x4*)(outp + (size_t)c * 16384 + p0) = x2v;
    }
  }
}

// ---------------------------------------------------------------------------
// k2: LN2 + MLP + residual. WG = (sequence s, 64-token group tg), 1024 thr.
// LDS (106496 B): h2 frags [4 mt][8 kt]x1KB @0 (32768),
//                 m1 frags [4 mt][16 kt]x1KB @32768 (65536),
//                 LN partials [16 w][64 tok] float2 @98304 (8192).
__global__ __launch_bounds__(1024, 4) void transformer_k2(
    const float* __restrict__ ln2g, const float* __restrict__ ln2b,
    const uint16_t* __restrict__ w1f, const uint16_t* __restrict__ w2f,
    const float* __restrict__ bm1, const float* __restrict__ bm2,
    float* __restrict__ out) {
  __shared__ __attribute__((aligned(16))) uint8_t lds[106496];
  const int tid = threadIdx.x;
  const int lane = tid & 63;
  const int w = tid >> 6;        // wave 0..15
  const int r = lane & 15, g = lane >> 4;
  const int bid = blockIdx.x;
  const int s = bid >> 2, tg = bid & 3;
  const int bb = s >> 6, nn = s & 63;
  float* outp = out + (size_t)bb * 4194304 + (size_t)nn * 256;
  const int tokbase = tg * 64;
  const f32x4 fz = {0.f, 0.f, 0.f, 0.f};

  // ---- LN2: thread (lane=token, w=c-group of 16) reads 16 x2 values --------
  float v[16];
  {
    float s1 = 0.f, s2 = 0.f;
    const int p = tokbase + lane;
#pragma unroll
    for (int j = 0; j < 16; ++j) {
      float t = outp[(size_t)(w * 16 + j) * 16384 + p];
      v[j] = t;
      s1 += t;
      s2 += t * t;
    }
    float2 pr; pr.x = s1; pr.y = s2;
    *(float2*)(lds + 98304 + (w * 64 + lane) * 8) = pr;
  }
  __syncthreads();
  {
    float su = 0.f, sq = 0.f;
#pragma unroll
    for (int w2 = 0; w2 < 16; ++w2) {
      float2 pr = *(const float2*)(lds + 98304 + (w2 * 64 + lane) * 8);
      su += pr.x;
      sq += pr.y;
    }
    float mu = su * (1.0f / 256.0f);
    float var = sq * (1.0f / 256.0f) - mu * mu;
    float rs = rsqrtf(var + 1e-5f);
    // normalize + pack h2 frags (frag-linear) into LDS
    uint32_t pk[8];
#pragma unroll
    for (int q = 0; q < 4; ++q) {
      int c0 = w * 16 + q * 4;
      f32x4 gv = *(const f32x4*)(ln2g + c0);
      f32x4 bv = *(const f32x4*)(ln2b + c0);
      float n0 = (v[q * 4 + 0] - mu) * rs * gv[0] + bv[0];
      float n1 = (v[q * 4 + 1] - mu) * rs * gv[1] + bv[1];
      float n2 = (v[q * 4 + 2] - mu) * rs * gv[2] + bv[2];
      float n3 = (v[q * 4 + 3] - mu) * rs * gv[3] + bv[3];
      pk[q * 2 + 0] = pk2(n0, n1);
      pk[q * 2 + 1] = pk2(n2, n3);
    }
    const int mt = lane >> 4;
    const int kt = w >> 1;
#pragma unroll
    for (int hblk = 0; hblk < 2; ++hblk) {
      int lanep = (lane & 15) + 32 * (w & 1) + 16 * hblk;
      uint4 t;
      t.x = pk[hblk * 4 + 0]; t.y = pk[hblk * 4 + 1];
      t.z = pk[hblk * 4 + 2]; t.w = pk[hblk * 4 + 3];
      *(uint4*)(lds + (mt * 8 + kt) * 1024 + lanep * 16) = t;
    }
  }
  __syncthreads();

  // ---- GEMM1: [64 tok][256 c] x W1^T[256][512]; wave owns 32 hidden cols ---
  f32x4 acc1[4][2];
#pragma unroll
  for (int mt = 0; mt < 4; ++mt)
#pragma unroll
    for (int nt = 0; nt < 2; ++nt) acc1[mt][nt] = fz;
#pragma unroll
  for (int kt = 0; kt < 8; ++kt) {
    B8 a[4];
#pragma unroll
    for (int mt = 0; mt < 4; ++mt)
      a[mt].q = *(const uint4*)(lds + (mt * 8 + kt) * 1024 + lane * 16);
#pragma unroll
    for (int nt = 0; nt < 2; ++nt) {
      B8 bfr;
      bfr.q = *(const uint4*)(w1f + (size_t)(((2 * w + nt) * 8 + kt) * 512) + lane * 8);
#pragma unroll
      for (int mt = 0; mt < 4; ++mt) acc1[mt][nt] = mfma16(a[mt], bfr, acc1[mt][nt]);
    }
  }
  // bias + exact GELU + scatter m1 C-frags into A-frag-linear LDS
#pragma unroll
  for (int nt = 0; nt < 2; ++nt) {
    float bias = bm1[(2 * w + nt) * 16 + r];
#pragma unroll
    for (int mt = 0; mt < 4; ++mt) {
#pragma unroll
      for (int i = 0; i < 4; ++i) {
        float vv = acc1[mt][nt][i] + bias;
        vv = 0.5f * vv * (1.0f + erff(vv * 0.70710678118654752440f));  // exact GELU
        int lanep = (4 * g + i) + 16 * (2 * nt + (r >> 3));
        *(uint16_t*)(lds + 32768 + (mt * 16 + w) * 1024 + lanep * 16 + (r & 7) * 2) = f2bf(vv);
      }
    }
  }
  __syncthreads();

  // ---- GEMM2: m1[64][512] x W2^T[512][256]; wave owns 16 output channels ---
  f32x4 acc2[4];
#pragma unroll
  for (int mt = 0; mt < 4; ++mt) acc2[mt] = fz;
#pragma unroll
  for (int kt = 0; kt < 16; ++kt) {
    B8 bfr;
    bfr.q = *(const uint4*)(w2f + (size_t)((w * 16 + kt) * 512) + lane * 8);
#pragma unroll
    for (int mt = 0; mt < 4; ++mt) {
      B8 a;
      a.q = *(const uint4*)(lds + 32768 + (mt * 16 + kt) * 1024 + lane * 16);
      acc2[mt] = mfma16(a, bfr, acc2[mt]);
    }
  }

  // ---- epilogue: out = x2 + mlp -------------------------------------------
  {
    int c = w * 16 + r;
    float bias = bm2[c];
#pragma unroll
    for (int mt = 0; mt < 4; ++mt) {
      int p0 = tokbase + 16 * mt + 4 * g;
      f32x4 res = *(const f32x4*)(outp + (size_t)c * 16384 + p0);
      f32x4 o;
#pragma unroll
      for (int i = 0; i < 4; ++i) o[i] = res[i] + acc2[mt][i] + bias;
      *(f32x4*)(outp + (size_t)c * 16384 + p0) = o;
    }
  }
}

// ---------------------------------------------------------------------------
extern "C" void kernel_launch(void* const* d_in, const int* in_sizes, int n_in,
                              void* d_out, int out_size, void* d_ws, size_t ws_size,
                              hipStream_t stream) {
  (void)in_sizes; (void)n_in; (void)out_size; (void)ws_size;
  const float* x     = (const float*)d_in[0];
  const float* wqkv  = (const float*)d_in[1];
  const float* wproj = (const float*)d_in[2];
  const float* bproj = (const float*)d_in[3];
  const float* ln1g  = (const float*)d_in[4];
  const float* ln1b  = (const float*)d_in[5];
  const float* ln2g  = (const float*)d_in[6];
  const float* ln2b  = (const float*)d_in[7];
  const float* w1    = (const float*)d_in[8];
  const float* bm1   = (const float*)d_in[9];
  const float* w2    = (const float*)d_in[10];
  const float* bm2   = (const float*)d_in[11];
  uint16_t* wbf = (uint16_t*)d_ws;        // 524288 bf16 weights (frag-linear)
  uint16_t* osc = wbf + 524288;           // 512*16*8*512 = 33554432 bf16 O frags
  float* out = (float*)d_out;

  transformer_prep<<<2048, 256, 0, stream>>>(wqkv, wproj, w1, w2, wbf);
  transformer_k1<<<512, 1024, 0, stream>>>(x, bproj, ln1g, ln1b, wbf, osc, out);
  transformer_k2<<<2048, 1024, 0, stream>>>(ln2g, ln2b, wbf + 262144, wbf + 393216, bm1, bm2, out);
}